// Round 1
// baseline (904.815 us; speedup 1.0000x reference)
//
#include <hip/hip_runtime.h>
#include <math.h>

#define NH 16
#define QL 2048
#define SL 2048
#define DD 64
#define BQ 64
#define BS 64
#define LSTR 68          // 68 floats = 272B row stride: float4-aligned, breaks pow2 bank stride
#define SCALE 0.125f     // 8.0 / 64

__global__ __launch_bounds__(256, 2) void attn_fp32_flash(
    const float* __restrict__ Qg, const float* __restrict__ Kg,
    const float* __restrict__ Vg, const int* __restrict__ plen_g,
    float* __restrict__ Og)
{
    __shared__ float sQ[BQ][LSTR];
    __shared__ float sKP[BS][LSTR];  // K during QK phase, P during PV phase (aliased)
    __shared__ float sV[BS][LSTR];

    const int blk = blockIdx.x;
    const int n  = blk & (NH - 1);          // interleave heads across CUs (load balance)
    const int q0 = (blk >> 4) * BQ;
    const int tid = (int)threadIdx.x;
    const int ty = tid >> 4;                 // 0..15 : query group
    const int tx = tid & 15;                 // 0..15 : key/dim group

    const int plen = plen_g[n];

    // ---- load Q tile (64x64 fp32) into LDS, coalesced float4 ----
    const float* Qbase = Qg + ((size_t)n * QL + q0) * DD;
    #pragma unroll
    for (int i = 0; i < 4; ++i) {
        int idx = tid + i * 256;             // float4 index in tile (1024 total)
        int r = idx >> 4;                    // 16 float4 per row
        int c = (idx & 15) << 2;
        *(float4*)(&sQ[r][c]) = *(const float4*)(Qbase + r * DD + c);
    }

    float m[4], l[4], acc[16];
    #pragma unroll
    for (int i = 0; i < 4; ++i) { m[i] = -INFINITY; l[i] = 0.f; }
    #pragma unroll
    for (int i = 0; i < 16; ++i) acc[i] = 0.f;

    for (int s0 = 0; s0 < SL; s0 += BS) {
        // skip tiles fully masked out: keep if any key < plen, or it's the diagonal tile
        if (!(s0 < plen || s0 == q0)) continue;

        __syncthreads();   // prev iteration done reading sKP/sV (also covers sQ first time)

        // ---- load K,V tiles ----
        const float* Kbase = Kg + ((size_t)n * SL + s0) * DD;
        const float* Vbase = Vg + ((size_t)n * SL + s0) * DD;
        #pragma unroll
        for (int i = 0; i < 4; ++i) {
            int idx = tid + i * 256;
            int r = idx >> 4;
            int c = (idx & 15) << 2;
            *(float4*)(&sKP[r][c]) = *(const float4*)(Kbase + r * DD + c);
            *(float4*)(&sV[r][c])  = *(const float4*)(Vbase + r * DD + c);
        }
        __syncthreads();

        // ---- QK^T: thread computes 4x4 scores [q=ty*4+i][s=tx*4+j] ----
        float sc[16];
        #pragma unroll
        for (int i = 0; i < 16; ++i) sc[i] = 0.f;
        #pragma unroll
        for (int d0 = 0; d0 < DD; d0 += 4) {
            float4 qv[4], kv[4];
            #pragma unroll
            for (int i = 0; i < 4; ++i) qv[i] = *(const float4*)(&sQ[ty * 4 + i][d0]);
            #pragma unroll
            for (int j = 0; j < 4; ++j) kv[j] = *(const float4*)(&sKP[tx * 4 + j][d0]);
            #pragma unroll
            for (int i = 0; i < 4; ++i) {
                #pragma unroll
                for (int j = 0; j < 4; ++j) {
                    sc[i * 4 + j] += qv[i].x * kv[j].x + qv[i].y * kv[j].y
                                   + qv[i].z * kv[j].z + qv[i].w * kv[j].w;
                }
            }
        }

        // ---- mask + scale + online softmax update ----
        #pragma unroll
        for (int i = 0; i < 4; ++i) {
            int q = q0 + ty * 4 + i;
            float rowmax = -INFINITY;
            #pragma unroll
            for (int j = 0; j < 4; ++j) {
                int s = s0 + tx * 4 + j;
                bool valid = (s < plen) || (s == q);
                float v = valid ? sc[i * 4 + j] * SCALE : -INFINITY;
                sc[i * 4 + j] = v;
                rowmax = fmaxf(rowmax, v);
            }
            #pragma unroll
            for (int off = 1; off < 16; off <<= 1)
                rowmax = fmaxf(rowmax, __shfl_xor(rowmax, off, 64));

            float mnew = fmaxf(m[i], rowmax);
            float alpha = (m[i] == -INFINITY) ? 0.f : __expf(m[i] - mnew);
            float psum = 0.f;
            #pragma unroll
            for (int j = 0; j < 4; ++j) {
                float p = (sc[i * 4 + j] == -INFINITY) ? 0.f : __expf(sc[i * 4 + j] - mnew);
                sc[i * 4 + j] = p;
                psum += p;
            }
            #pragma unroll
            for (int off = 1; off < 16; off <<= 1)
                psum += __shfl_xor(psum, off, 64);

            l[i] = l[i] * alpha + psum;
            m[i] = mnew;
            #pragma unroll
            for (int j = 0; j < 4; ++j) acc[i * 4 + j] *= alpha;
        }

        // ---- P -> LDS (reuse K buffer) ----
        __syncthreads();   // everyone done reading sKP as K
        #pragma unroll
        for (int i = 0; i < 4; ++i)
            #pragma unroll
            for (int j = 0; j < 4; ++j)
                sKP[ty * 4 + i][tx * 4 + j] = sc[i * 4 + j];
        __syncthreads();

        // ---- PV: acc[q=ty*4+i][d=tx*4+j] += sum_s P[q][s] * V[s][d] ----
        #pragma unroll
        for (int ss = 0; ss < BS; ss += 4) {
            float4 pv[4], vv[4];
            #pragma unroll
            for (int i = 0; i < 4; ++i) pv[i] = *(const float4*)(&sKP[ty * 4 + i][ss]);
            #pragma unroll
            for (int r = 0; r < 4; ++r) vv[r] = *(const float4*)(&sV[ss + r][tx * 4]);
            #pragma unroll
            for (int i = 0; i < 4; ++i) {
                acc[i * 4 + 0] += pv[i].x * vv[0].x + pv[i].y * vv[1].x + pv[i].z * vv[2].x + pv[i].w * vv[3].x;
                acc[i * 4 + 1] += pv[i].x * vv[0].y + pv[i].y * vv[1].y + pv[i].z * vv[2].y + pv[i].w * vv[3].y;
                acc[i * 4 + 2] += pv[i].x * vv[0].z + pv[i].y * vv[1].z + pv[i].z * vv[2].z + pv[i].w * vv[3].z;
                acc[i * 4 + 3] += pv[i].x * vv[0].w + pv[i].y * vv[1].w + pv[i].z * vv[2].w + pv[i].w * vv[3].w;
            }
        }
    }

    // ---- epilogue: O = acc / l  (l > 0 guaranteed: diagonal key always valid) ----
    #pragma unroll
    for (int i = 0; i < 4; ++i) {
        float inv = 1.0f / l[i];
        int q = q0 + ty * 4 + i;
        float4 o;
        o.x = acc[i * 4 + 0] * inv;
        o.y = acc[i * 4 + 1] * inv;
        o.z = acc[i * 4 + 2] * inv;
        o.w = acc[i * 4 + 3] * inv;
        *(float4*)(Og + ((size_t)n * QL + q) * DD + tx * 4) = o;
    }
}

extern "C" void kernel_launch(void* const* d_in, const int* in_sizes, int n_in,
                              void* d_out, int out_size, void* d_ws, size_t ws_size,
                              hipStream_t stream) {
    const float* Qg   = (const float*)d_in[0];
    const float* Kg   = (const float*)d_in[1];
    const float* Vg   = (const float*)d_in[2];
    const int*   plen = (const int*)d_in[3];
    float* Og = (float*)d_out;

    dim3 grid(NH * (QL / BQ));   // 512 blocks
    attn_fp32_flash<<<grid, 256, 0, stream>>>(Qg, Kg, Vg, plen, Og);
}

// Round 2
// 150.994 us; speedup vs baseline: 5.9924x; 5.9924x over previous
//
#include <hip/hip_runtime.h>
#include <math.h>

#define NH 16
#define QL 2048
#define SL 2048
#define DD 64
#define BQ 64
#define BS 64
#define PSTR 72          // ushort row stride: multiple of 8 (16B-aligned b128 reads), quad-spreads banks
#define SCALE 0.125f     // 8.0 / 64

typedef __attribute__((ext_vector_type(8))) short short8;       // 8 x bf16 MFMA A/B frag
typedef __attribute__((ext_vector_type(4))) float floatx4;      // MFMA C/D frag
typedef __attribute__((ext_vector_type(4))) unsigned short ushort4v;

__device__ __forceinline__ unsigned short f2bf(float x) {       // RNE float->bf16
    unsigned u = __float_as_uint(x);
    u += 0x7FFFu + ((u >> 16) & 1u);
    return (unsigned short)(u >> 16);
}

__global__ __launch_bounds__(256, 4) void attn_mfma_flash(
    const float* __restrict__ Qg, const float* __restrict__ Kg,
    const float* __restrict__ Vg, const int* __restrict__ plen_g,
    float* __restrict__ Og)
{
    __shared__ unsigned short sQ[BQ * PSTR];        // Q tile, bf16 [q][d]
    __shared__ unsigned short sK[BS * PSTR];        // K tile, bf16 [s][d]
    __shared__ unsigned short sVt[DD * PSTR];       // V^T tile, bf16 [d][s ^ (d&0x38)]
    __shared__ unsigned short sP[4 * 16 * PSTR];    // per-wave P tile, bf16 [q][s]

    const int blk  = blockIdx.x;
    const int n    = blk & (NH - 1);                // interleave heads for load balance
    const int q0   = (blk >> 4) * BQ;
    const int tid  = (int)threadIdx.x;
    const int wave = tid >> 6;
    const int lane = tid & 63;
    const int quad = lane >> 4;
    const int l16  = lane & 15;
    const int plen = plen_g[n];

    // ---- stage Q tile (fp32 -> bf16), coalesced float4 ----
    const float* Qbase = Qg + ((size_t)n * QL + q0) * DD;
    #pragma unroll
    for (int i = 0; i < 4; ++i) {
        int idx = tid + i * 256;
        int r = idx >> 4, c = (idx & 15) << 2;
        float4 v = *(const float4*)(Qbase + r * DD + c);
        ushort4v h = { f2bf(v.x), f2bf(v.y), f2bf(v.z), f2bf(v.w) };
        *(ushort4v*)(&sQ[r * PSTR + c]) = h;
    }

    floatx4 acc[4];                 // O accum, C-layout: row=quad*4+r, col(d)=dt*16+l16
    float m[4], l[4];
    #pragma unroll
    for (int i = 0; i < 4; ++i) {
        acc[i] = (floatx4){0.f, 0.f, 0.f, 0.f};
        m[i] = -INFINITY; l[i] = 0.f;
    }

    for (int s0 = 0; s0 < SL; s0 += BS) {
        // keep tile iff any key valid: prefix block or the diagonal tile
        if (!(s0 < plen || s0 == q0)) continue;
        __syncthreads();            // prior iter done reading sK/sVt (covers sQ on first iter)

        // ---- stage K tile + transposed/swizzled V tile ----
        const float* Kb = Kg + ((size_t)n * SL + s0) * DD;
        const float* Vb = Vg + ((size_t)n * SL + s0) * DD;
        #pragma unroll
        for (int i = 0; i < 4; ++i) {
            int idx = tid + i * 256;
            int r = idx >> 4, c = (idx & 15) << 2;
            float4 kv = *(const float4*)(Kb + r * DD + c);
            ushort4v hk = { f2bf(kv.x), f2bf(kv.y), f2bf(kv.z), f2bf(kv.w) };
            *(ushort4v*)(&sK[r * PSTR + c]) = hk;
            float4 vv = *(const float4*)(Vb + r * DD + c);
            unsigned short hv0 = f2bf(vv.x), hv1 = f2bf(vv.y), hv2 = f2bf(vv.z), hv3 = f2bf(vv.w);
            // element V[s=r][d=c+k] -> sVt[d][r ^ (d&0x38)]  (XOR keeps 8-blocks intact for b128 reads)
            sVt[(c + 0) * PSTR + (r ^ ((c + 0) & 0x38))] = hv0;
            sVt[(c + 1) * PSTR + (r ^ ((c + 1) & 0x38))] = hv1;
            sVt[(c + 2) * PSTR + (r ^ ((c + 2) & 0x38))] = hv2;
            sVt[(c + 3) * PSTR + (r ^ ((c + 3) & 0x38))] = hv3;
        }
        __syncthreads();

        // ---- QK^T: wave computes S[16 q][64 s], 8 MFMAs ----
        floatx4 sf[4];
        #pragma unroll
        for (int ct = 0; ct < 4; ++ct) sf[ct] = (floatx4){0.f, 0.f, 0.f, 0.f};
        #pragma unroll
        for (int ks = 0; ks < 2; ++ks) {
            short8 aQ = *(const short8*)(&sQ[(wave * 16 + l16) * PSTR + ks * 32 + quad * 8]);
            #pragma unroll
            for (int ct = 0; ct < 4; ++ct) {
                short8 bK = *(const short8*)(&sK[(ct * 16 + l16) * PSTR + ks * 32 + quad * 8]);
                sf[ct] = __builtin_amdgcn_mfma_f32_16x16x32_bf16(aQ, bK, sf[ct], 0, 0, 0);
            }
        }

        // ---- mask + scale + online softmax; emit P (bf16) into per-wave LDS ----
        float alpha[4];
        #pragma unroll
        for (int r = 0; r < 3 + 1; ++r) {
            int q = q0 + wave * 16 + quad * 4 + r;
            float v[4]; float mx = -INFINITY;
            #pragma unroll
            for (int ct = 0; ct < 4; ++ct) {
                int s = s0 + ct * 16 + l16;
                bool valid = (s < plen) || (s == q);
                v[ct] = valid ? sf[ct][r] * SCALE : -INFINITY;
                mx = fmaxf(mx, v[ct]);
            }
            #pragma unroll
            for (int off = 1; off < 16; off <<= 1)
                mx = fmaxf(mx, __shfl_xor(mx, off, 64));

            float mnew = fmaxf(m[r], mx);
            float a = __expf(m[r] - mnew);          // m=-inf -> 0, mnew always finite
            float ps = 0.f;
            unsigned short* pw = &sP[(wave * 16 + quad * 4 + r) * PSTR + l16];
            #pragma unroll
            for (int ct = 0; ct < 4; ++ct) {
                float p = __expf(v[ct] - mnew);     // v=-inf -> 0
                ps += p;
                pw[ct * 16] = f2bf(p);
            }
            #pragma unroll
            for (int off = 1; off < 16; off <<= 1)
                ps += __shfl_xor(ps, off, 64);

            l[r] = l[r] * a + ps;
            m[r] = mnew;
            alpha[r] = a;
        }

        // rescale O accumulator (rows match alpha rows: quad*4+r)
        #pragma unroll
        for (int dt = 0; dt < 4; ++dt)
            #pragma unroll
            for (int r = 0; r < 4; ++r)
                acc[dt][r] *= alpha[r];

        // ---- PV: O[16 q][64 d] += P[16 q][64 s] * V[64 s][64 d], 8 MFMAs ----
        // (wave-private sP: same-wave ds_write->ds_read ordering via lgkmcnt, no barrier)
        #pragma unroll
        for (int ks = 0; ks < 2; ++ks) {
            short8 aP = *(const short8*)(&sP[(wave * 16 + l16) * PSTR + ks * 32 + quad * 8]);
            #pragma unroll
            for (int dt = 0; dt < 4; ++dt) {
                int d = dt * 16 + l16;
                short8 bV = *(const short8*)(&sVt[d * PSTR + ((ks * 32 + quad * 8) ^ (d & 0x38))]);
                acc[dt] = __builtin_amdgcn_mfma_f32_16x16x32_bf16(aP, bV, acc[dt], 0, 0, 0);
            }
        }
    }

    // ---- epilogue: O = acc / l ----
    #pragma unroll
    for (int r = 0; r < 4; ++r) {
        float inv = 1.0f / l[r];
        int q = q0 + wave * 16 + quad * 4 + r;
        float* ob = Og + ((size_t)n * QL + q) * DD;
        #pragma unroll
        for (int dt = 0; dt < 4; ++dt)
            ob[dt * 16 + l16] = acc[dt][r] * inv;
    }
}

extern "C" void kernel_launch(void* const* d_in, const int* in_sizes, int n_in,
                              void* d_out, int out_size, void* d_ws, size_t ws_size,
                              hipStream_t stream) {
    const float* Qg   = (const float*)d_in[0];
    const float* Kg   = (const float*)d_in[1];
    const float* Vg   = (const float*)d_in[2];
    const int*   plen = (const int*)d_in[3];
    float* Og = (float*)d_out;

    dim3 grid(NH * (QL / BQ));   // 512 blocks, 4 waves each
    attn_mfma_flash<<<grid, 256, 0, stream>>>(Qg, Kg, Vg, plen, Og);
}

// Round 3
// 116.681 us; speedup vs baseline: 7.7546x; 1.2941x over previous
//
#include <hip/hip_runtime.h>
#include <math.h>

#define NH 16
#define QL 2048
#define SL 2048
#define DD 64
#define PSTR 72
#define QK_SCALE_LOG2E 0.1803368801111f   // (8/64) * log2(e): fold softmax scale + ln2 into Q

typedef __attribute__((ext_vector_type(8))) short short8;
typedef __attribute__((ext_vector_type(4))) float floatx4;
typedef __attribute__((ext_vector_type(4))) unsigned short ushort4v;
typedef __attribute__((ext_vector_type(8))) unsigned short ushort8v;

__device__ __forceinline__ unsigned short f2bf(float x) {   // RNE fp32->bf16
    unsigned u = __float_as_uint(x);
    u += 0x7FFFu + ((u >> 16) & 1u);
    return (unsigned short)(u >> 16);
}

// async global->LDS, 16B per lane; LDS dest = wave-uniform base + lane*16
__device__ __forceinline__ void gld16(const unsigned short* g, unsigned short* l) {
    __builtin_amdgcn_global_load_lds(
        (const __attribute__((address_space(1))) unsigned int*)g,
        (__attribute__((address_space(3))) unsigned int*)l, 16, 0, 0);
}

// ---------------- pre-conversion: Q*(scale*log2e) and K -> bf16 ----------------
__global__ __launch_bounds__(256) void convqk(
    const float* __restrict__ Qf, const float* __restrict__ Kf,
    unsigned short* __restrict__ Qb, unsigned short* __restrict__ Kb)
{
    int idx = blockIdx.x * 256 + threadIdx.x;          // float4 index, NH*QL*DD/4 total
    const float4* src; unsigned short* dst; float scale;
    if (blockIdx.y == 0) { src = (const float4*)Qf; dst = Qb; scale = QK_SCALE_LOG2E; }
    else                 { src = (const float4*)Kf; dst = Kb; scale = 1.0f; }
    float4 v = src[idx];
    ushort4v h = { f2bf(v.x * scale), f2bf(v.y * scale), f2bf(v.z * scale), f2bf(v.w * scale) };
    *(ushort4v*)(dst + (size_t)idx * 4) = h;
}

// ---------------- V -> V^T (bf16), per-head [d][s] ----------------
__global__ __launch_bounds__(256) void transv(
    const float* __restrict__ Vf, unsigned short* __restrict__ Vtb)
{
    __shared__ unsigned short sT[64][PSTR];
    int bx = blockIdx.x;                               // 0..511 : 16 heads x 32 s-tiles
    int n = bx >> 5, stile = bx & 31, s0 = stile * 64;
    int tid = (int)threadIdx.x;
    const float* vb = Vf + ((size_t)n * SL + s0) * DD;
    #pragma unroll
    for (int i = 0; i < 4; ++i) {
        int idx = tid + i * 256;
        int r = idx >> 4, c = (idx & 15) << 2;
        float4 v = *(const float4*)(vb + r * DD + c);
        sT[c + 0][r] = f2bf(v.x);
        sT[c + 1][r] = f2bf(v.y);
        sT[c + 2][r] = f2bf(v.z);
        sT[c + 3][r] = f2bf(v.w);
    }
    __syncthreads();
    int d = tid >> 2, sg = tid & 3;
    unsigned short* out = Vtb + (size_t)n * DD * SL + (size_t)d * SL + s0 + sg * 16;
    ushort8v a, b;
    #pragma unroll
    for (int i = 0; i < 8; ++i) { a[i] = sT[d][sg * 16 + i]; b[i] = sT[d][sg * 16 + 8 + i]; }
    *(ushort8v*)(out) = a;
    *(ushort8v*)(out + 8) = b;
}

// ---------------- attention, split-S, fixed-max softmax ----------------
__global__ __launch_bounds__(256, 4) void attn_mfma_split(
    const unsigned short* __restrict__ Qb, const unsigned short* __restrict__ Kb,
    const unsigned short* __restrict__ Vtb, const int* __restrict__ plen_g,
    float* __restrict__ Op, float* __restrict__ Lp, int spl)
{
    // 64x64 bf16 tiles, row = 64 ushorts (128B, NO pad: required by global_load_lds),
    // chunk c of row r stored at chunk slot c ^ (r&7) (swizzle applied on global fetch side)
    __shared__ unsigned short sQ[64 * 64];
    __shared__ unsigned short sK[64 * 64];
    __shared__ unsigned short sVt[64 * 64];
    __shared__ unsigned short sP[4 * 16 * PSTR];   // per-wave P[q][s]

    const int blk = blockIdx.x;
    const int n  = blk & (NH - 1);
    const int qt = blk >> 4;
    const int q0 = qt * 64;
    const int sp = blockIdx.y;
    const int sbeg = sp * spl;
    const int plen = plen_g[n];
    const bool hasdiag = (q0 >= sbeg) && (q0 < sbeg + spl);
    if (!((sbeg < plen) || hasdiag)) return;       // must match combine's predicate

    const int tid  = (int)threadIdx.x;
    const int wave = tid >> 6, lane = tid & 63, quad = lane >> 4, l16 = lane & 15;

    // ---- stage Q tile once ----
    {
        const unsigned short* qg = Qb + ((size_t)(n * QL + q0)) * DD;
        #pragma unroll
        for (int j = 0; j < 2; ++j) {
            int seg = wave * 2 + j;
            int r = seg * 8 + (lane >> 3);
            int cg = (lane & 7) ^ (r & 7);
            gld16(qg + r * DD + cg * 8, sQ + seg * 512);
        }
    }

    floatx4 acc[4];
    #pragma unroll
    for (int dt = 0; dt < 4; ++dt) acc[dt] = (floatx4){0.f, 0.f, 0.f, 0.f};
    float lsum = 0.f;                              // per-lane partial of l for q = q0+wave*16+l16

    const int ntile = spl >> 6;
    for (int t = 0; t < ntile; ++t) {
        const int s0 = sbeg + t * 64;
        if (!((s0 < plen) || (s0 == q0))) continue;
        __syncthreads();                           // prior tile's reads done

        const unsigned short* kg = Kb + ((size_t)(n * SL + s0)) * DD;
        const unsigned short* vg = Vtb + (size_t)n * DD * SL + s0;
        #pragma unroll
        for (int j = 0; j < 2; ++j) {
            int seg = wave * 2 + j;
            int r = seg * 8 + (lane >> 3);
            int cg = (lane & 7) ^ (r & 7);
            gld16(kg + r * DD + cg * 8, sK + seg * 512);
            gld16(vg + (size_t)r * SL + cg * 8, sVt + seg * 512);
        }
        __syncthreads();

        // ---- S^T = K·Q^T : D[s=st*16+quad*4+r][q=l16] ----
        floatx4 sf[4];
        #pragma unroll
        for (int st2 = 0; st2 < 4; ++st2) sf[st2] = (floatx4){0.f, 0.f, 0.f, 0.f};
        #pragma unroll
        for (int ks = 0; ks < 2; ++ks) {
            int qrow = wave * 16 + l16;
            short8 bQ = *(const short8*)(sQ + qrow * 64 + (((ks * 4 + quad) ^ (qrow & 7)) * 8));
            #pragma unroll
            for (int st2 = 0; st2 < 4; ++st2) {
                int krow = st2 * 16 + l16;
                short8 aK = *(const short8*)(sK + krow * 64 + (((ks * 4 + quad) ^ (krow & 7)) * 8));
                sf[st2] = __builtin_amdgcn_mfma_f32_16x16x32_bf16(aK, bQ, sf[st2], 0, 0, 0);
            }
        }

        // ---- fixed-max softmax: p = exp2(prescaled score); no cross-lane ops ----
        const int qcol = q0 + wave * 16 + l16;
        unsigned short* pw = sP + (wave * 16 + l16) * PSTR;
        if (s0 + 64 <= plen) {                     // fully-valid tile: no masking
            #pragma unroll
            for (int st2 = 0; st2 < 4; ++st2) {
                float p0 = exp2f(sf[st2][0]);
                float p1 = exp2f(sf[st2][1]);
                float p2 = exp2f(sf[st2][2]);
                float p3 = exp2f(sf[st2][3]);
                lsum += (p0 + p1) + (p2 + p3);
                ushort4v pk = { f2bf(p0), f2bf(p1), f2bf(p2), f2bf(p3) };
                *(ushort4v*)(pw + st2 * 16 + quad * 4) = pk;   // P^T-pack: r contiguous in s
            }
        } else {
            #pragma unroll
            for (int st2 = 0; st2 < 4; ++st2) {
                float p[4];
                #pragma unroll
                for (int r = 0; r < 4; ++r) {
                    int s = s0 + st2 * 16 + quad * 4 + r;
                    bool valid = (s < plen) || (s == qcol);
                    p[r] = exp2f(valid ? sf[st2][r] : -INFINITY);
                    lsum += p[r];
                }
                ushort4v pk = { f2bf(p[0]), f2bf(p[1]), f2bf(p[2]), f2bf(p[3]) };
                *(ushort4v*)(pw + st2 * 16 + quad * 4) = pk;
            }
        }

        // ---- PV: O[q][d] += P·V (A = P rows q, B = V^T rows d) ----
        #pragma unroll
        for (int ks = 0; ks < 2; ++ks) {
            short8 aP = *(const short8*)(sP + (wave * 16 + l16) * PSTR + ks * 32 + quad * 8);
            #pragma unroll
            for (int dt = 0; dt < 4; ++dt) {
                int vrow = dt * 16 + l16;
                short8 bV = *(const short8*)(sVt + vrow * 64 + (((ks * 4 + quad) ^ (vrow & 7)) * 8));
                acc[dt] = __builtin_amdgcn_mfma_f32_16x16x32_bf16(aP, bV, acc[dt], 0, 0, 0);
            }
        }
    }

    // ---- epilogue: unnormalized partials ----
    lsum += __shfl_xor(lsum, 16, 64);
    lsum += __shfl_xor(lsum, 32, 64);
    if (quad == 0)
        Lp[((size_t)sp * NH + n) * QL + q0 + wave * 16 + l16] = lsum;

    float* ob = Op + (((size_t)sp * NH + n) * QL + q0) * DD;
    #pragma unroll
    for (int r = 0; r < 4; ++r) {
        int ql = wave * 16 + quad * 4 + r;
        #pragma unroll
        for (int dt = 0; dt < 4; ++dt)
            ob[(size_t)ql * DD + dt * 16 + l16] = acc[dt][r];
    }
}

// ---------------- combine: O = sum(Op) / sum(Lp) over contributing splits ----------------
__global__ __launch_bounds__(256) void combine(
    const float* __restrict__ Op, const float* __restrict__ Lp,
    const int* __restrict__ plen_g, float* __restrict__ Og, int nsplit, int spl)
{
    int idx = blockIdx.x * 256 + (int)threadIdx.x;    // float4 index, NH*QL*DD/4
    int d4 = idx & 15;
    int q  = (idx >> 4) & (QL - 1);
    int n  = idx >> 15;                               // QL*16 float4 per head = 2^15
    int plen = plen_g[n];
    int spd = q / spl;                                // split holding the diagonal
    float4 s = {0.f, 0.f, 0.f, 0.f};
    float l = 0.f;
    for (int sp = 0; sp < nsplit; ++sp) {
        if ((sp * spl < plen) || (sp == spd)) {       // same predicate as attn early-exit
            const float* ob = Op + (((size_t)sp * NH + n) * QL + q) * DD;
            float4 v = *(const float4*)(ob + d4 * 4);
            s.x += v.x; s.y += v.y; s.z += v.z; s.w += v.w;
            l += Lp[((size_t)sp * NH + n) * QL + q];
        }
    }
    float inv = 1.0f / l;
    float4 o = { s.x * inv, s.y * inv, s.z * inv, s.w * inv };
    *(float4*)(Og + ((size_t)n * QL + q) * DD + d4 * 4) = o;
}

extern "C" void kernel_launch(void* const* d_in, const int* in_sizes, int n_in,
                              void* d_out, int out_size, void* d_ws, size_t ws_size,
                              hipStream_t stream) {
    const float* Qf   = (const float*)d_in[0];
    const float* Kf   = (const float*)d_in[1];
    const float* Vf   = (const float*)d_in[2];
    const int*   plen = (const int*)d_in[3];
    float* Og = (float*)d_out;

    char* ws = (char*)d_ws;
    unsigned short* Qb  = (unsigned short*)(ws);
    unsigned short* Kb  = (unsigned short*)(ws + (4u << 20));
    unsigned short* Vtb = (unsigned short*)(ws + (8u << 20));
    float* Op = (float*)(ws + (12u << 20));

    const size_t op_bytes = (size_t)NH * QL * DD * 4;   // 8 MB per split
    const size_t lp_bytes = (size_t)NH * QL * 4;        // 128 KB per split
    int nsplit = 1;
    if (ws_size >= (12u << 20) + 4 * (op_bytes + lp_bytes)) nsplit = 4;
    else if (ws_size >= (12u << 20) + 2 * (op_bytes + lp_bytes)) nsplit = 2;
    float* Lp = (float*)(ws + (12u << 20) + (size_t)nsplit * op_bytes);
    int spl = SL / nsplit;

    convqk<<<dim3(2048, 2), 256, 0, stream>>>(Qf, Kf, Qb, Kb);
    transv<<<512, 256, 0, stream>>>(Vf, Vtb);
    attn_mfma_split<<<dim3(NH * (QL / 64), nsplit), 256, 0, stream>>>(Qb, Kb, Vtb, plen, Op, Lp, spl);
    combine<<<2048, 256, 0, stream>>>(Op, Lp, plen, Og, nsplit, spl);
}

// Round 4
// 114.550 us; speedup vs baseline: 7.8988x; 1.0186x over previous
//
#include <hip/hip_runtime.h>
#include <math.h>

#define NH 16
#define QL 2048
#define SL 2048
#define DD 64
#define PSTR 72
#define QK_SCALE_LOG2E 0.1803368801111f   // (8/64) * log2(e): fold softmax scale + ln2 into Q

typedef __attribute__((ext_vector_type(8))) short short8;
typedef __attribute__((ext_vector_type(4))) float floatx4;
typedef __attribute__((ext_vector_type(4))) unsigned short ushort4v;
typedef __attribute__((ext_vector_type(8))) unsigned short ushort8v;

__device__ __forceinline__ unsigned short f2bf(float x) {   // RNE fp32->bf16
    unsigned u = __float_as_uint(x);
    u += 0x7FFFu + ((u >> 16) & 1u);
    return (unsigned short)(u >> 16);
}

// async global->LDS, 16B per lane; LDS dest = wave-uniform base + lane*16
__device__ __forceinline__ void gld16(const unsigned short* g, unsigned short* l) {
    __builtin_amdgcn_global_load_lds(
        (const __attribute__((address_space(1))) unsigned int*)g,
        (__attribute__((address_space(3))) unsigned int*)l, 16, 0, 0);
}

// ---------------- pre-conversion: Q*(scale*log2e) and K -> bf16 ----------------
__global__ __launch_bounds__(256) void convqk(
    const float* __restrict__ Qf, const float* __restrict__ Kf,
    unsigned short* __restrict__ Qb, unsigned short* __restrict__ Kb)
{
    int idx = blockIdx.x * 256 + threadIdx.x;
    const float4* src; unsigned short* dst; float scale;
    if (blockIdx.y == 0) { src = (const float4*)Qf; dst = Qb; scale = QK_SCALE_LOG2E; }
    else                 { src = (const float4*)Kf; dst = Kb; scale = 1.0f; }
    float4 v = src[idx];
    ushort4v h = { f2bf(v.x * scale), f2bf(v.y * scale), f2bf(v.z * scale), f2bf(v.w * scale) };
    *(ushort4v*)(dst + (size_t)idx * 4) = h;
}

// ---------------- V -> V^T (bf16), per-head [d][s] ----------------
__global__ __launch_bounds__(256) void transv(
    const float* __restrict__ Vf, unsigned short* __restrict__ Vtb)
{
    __shared__ unsigned short sT[64][PSTR];
    int bx = blockIdx.x;                               // 16 heads x 32 s-tiles
    int n = bx >> 5, stile = bx & 31, s0 = stile * 64;
    int tid = (int)threadIdx.x;
    const float* vb = Vf + ((size_t)n * SL + s0) * DD;
    #pragma unroll
    for (int i = 0; i < 4; ++i) {
        int idx = tid + i * 256;
        int r = idx >> 4, c = (idx & 15) << 2;
        float4 v = *(const float4*)(vb + r * DD + c);
        sT[c + 0][r] = f2bf(v.x);
        sT[c + 1][r] = f2bf(v.y);
        sT[c + 2][r] = f2bf(v.z);
        sT[c + 3][r] = f2bf(v.w);
    }
    __syncthreads();
    int d = tid >> 2, sg = tid & 3;
    unsigned short* out = Vtb + (size_t)n * DD * SL + (size_t)d * SL + s0 + sg * 16;
    ushort8v a, b;
    #pragma unroll
    for (int i = 0; i < 8; ++i) { a[i] = sT[d][sg * 16 + i]; b[i] = sT[d][sg * 16 + 8 + i]; }
    *(ushort8v*)(out) = a;
    *(ushort8v*)(out + 8) = b;
}

// ---------------- attention: split-S, fixed-max softmax, double-buffered K/V ----------------
__global__ __launch_bounds__(256, 3) void attn_mfma_split(
    const unsigned short* __restrict__ Qb, const unsigned short* __restrict__ Kb,
    const unsigned short* __restrict__ Vtb, const int* __restrict__ plen_g,
    float* __restrict__ Op, float* __restrict__ Lp, int spl)
{
    // 64x64 bf16 tiles, row = 64 ushorts (128B, NO pad: global_load_lds needs lane*16 dest),
    // chunk c of row r stored at slot c ^ (r&7) (swizzle applied on the global fetch side)
    __shared__ unsigned short sQ[64 * 64];
    __shared__ unsigned short sK[2][64 * 64];
    __shared__ unsigned short sVt[2][64 * 64];
    __shared__ unsigned short sP[4 * 16 * PSTR];   // per-wave P[q][s]

    const int blk = blockIdx.x;
    const int n  = blk & (NH - 1);
    const int qt = blk >> 4;
    const int q0 = qt * 64;
    const int sp = blockIdx.y;
    const int sbeg = sp * spl;
    const int plen = plen_g[n];
    const int ntile = spl >> 6;
    const bool hasdiag = (q0 >= sbeg) && (q0 < sbeg + spl);
    if (!((sbeg < plen) || hasdiag)) return;       // must match combine's predicate

    const int tid  = (int)threadIdx.x;
    const int wave = tid >> 6, lane = tid & 63, quad = lane >> 4, l16 = lane & 15;

    // active tiles: [0, base) prefix tiles + the diagonal tile if beyond base
    int rem  = plen - sbeg;
    int base = (rem > 0) ? min((rem + 63) >> 6, ntile) : 0;
    int td   = hasdiag ? ((q0 - sbeg) >> 6) : -1;
    int total = base + ((td >= base) ? 1 : 0);

    const unsigned short* kh = Kb  + (size_t)n * SL * DD;
    const unsigned short* vh = Vtb + (size_t)n * DD * SL;

    // per-wave staging lane mapping (shared by all gld16 rounds)
    const int seg0 = wave * 2, seg1 = wave * 2 + 1;
    const int r0 = seg0 * 8 + (lane >> 3), r1 = seg1 * 8 + (lane >> 3);
    const int cg0 = ((lane & 7) ^ (r0 & 7)) * 8, cg1 = ((lane & 7) ^ (r1 & 7)) * 8;

    // ---- prologue: stage Q tile + first K/V tile into buf 0 ----
    {
        const unsigned short* qg = Qb + ((size_t)(n * QL + q0)) * DD;
        gld16(qg + r0 * DD + cg0, sQ + seg0 * 512);
        gld16(qg + r1 * DD + cg1, sQ + seg1 * 512);
        int t0 = (0 < base) ? 0 : td;
        const unsigned short* kg = kh + (size_t)(sbeg + t0 * 64) * DD;
        const unsigned short* vg = vh + (sbeg + t0 * 64);
        gld16(kg + r0 * DD + cg0, sK[0] + seg0 * 512);
        gld16(kg + r1 * DD + cg1, sK[0] + seg1 * 512);
        gld16(vg + (size_t)r0 * SL + cg0, sVt[0] + seg0 * 512);
        gld16(vg + (size_t)r1 * SL + cg1, sVt[0] + seg1 * 512);
    }

    floatx4 acc[4];
    #pragma unroll
    for (int dt = 0; dt < 4; ++dt) acc[dt] = (floatx4){0.f, 0.f, 0.f, 0.f};
    float lsum = 0.f;                              // per-lane partial of l for q = q0+wave*16+l16

    const int qrow = wave * 16 + l16;
    short8 bQ0, bQ1;                               // Q fragments, hoisted (loop-invariant)

    for (int i = 0; i < total; ++i) {
        __syncthreads();                           // buf[i&1] staged; prior reads of buf[(i+1)&1] done

        // prefetch tile i+1 into the other buffer (in flight during this tile's compute)
        if (i + 1 < total) {
            int tn = (i + 1 < base) ? (i + 1) : td;
            const unsigned short* kg = kh + (size_t)(sbeg + tn * 64) * DD;
            const unsigned short* vg = vh + (sbeg + tn * 64);
            unsigned short* dk = sK[(i + 1) & 1];
            unsigned short* dv = sVt[(i + 1) & 1];
            gld16(kg + r0 * DD + cg0, dk + seg0 * 512);
            gld16(kg + r1 * DD + cg1, dk + seg1 * 512);
            gld16(vg + (size_t)r0 * SL + cg0, dv + seg0 * 512);
            gld16(vg + (size_t)r1 * SL + cg1, dv + seg1 * 512);
        }
        if (i == 0) {
            bQ0 = *(const short8*)(sQ + qrow * 64 + (((0 * 4 + quad) ^ (qrow & 7)) * 8));
            bQ1 = *(const short8*)(sQ + qrow * 64 + (((1 * 4 + quad) ^ (qrow & 7)) * 8));
        }

        const unsigned short* sk = sK[i & 1];
        const unsigned short* sv = sVt[i & 1];
        const int t  = (i < base) ? i : td;
        const int s0 = sbeg + t * 64;

        // ---- S^T = K·Q^T : D[s=st2*16+quad*4+r][q=l16] ----
        floatx4 sf[4];
        #pragma unroll
        for (int st2 = 0; st2 < 4; ++st2) sf[st2] = (floatx4){0.f, 0.f, 0.f, 0.f};
        #pragma unroll
        for (int st2 = 0; st2 < 4; ++st2) {
            int krow = st2 * 16 + l16;
            short8 aK0 = *(const short8*)(sk + krow * 64 + (((0 * 4 + quad) ^ (krow & 7)) * 8));
            short8 aK1 = *(const short8*)(sk + krow * 64 + (((1 * 4 + quad) ^ (krow & 7)) * 8));
            sf[st2] = __builtin_amdgcn_mfma_f32_16x16x32_bf16(aK0, bQ0, sf[st2], 0, 0, 0);
            sf[st2] = __builtin_amdgcn_mfma_f32_16x16x32_bf16(aK1, bQ1, sf[st2], 0, 0, 0);
        }

        // ---- fixed-max softmax: p = exp2(prescaled score); no cross-lane ops ----
        const int qcol = q0 + qrow;
        unsigned short* pw = sP + qrow * PSTR;
        if (s0 + 64 <= plen) {                     // fully-valid tile
            #pragma unroll
            for (int st2 = 0; st2 < 4; ++st2) {
                float p0 = __builtin_amdgcn_exp2f(sf[st2][0]);
                float p1 = __builtin_amdgcn_exp2f(sf[st2][1]);
                float p2 = __builtin_amdgcn_exp2f(sf[st2][2]);
                float p3 = __builtin_amdgcn_exp2f(sf[st2][3]);
                lsum += (p0 + p1) + (p2 + p3);
                ushort4v pk = { f2bf(p0), f2bf(p1), f2bf(p2), f2bf(p3) };
                *(ushort4v*)(pw + st2 * 16 + quad * 4) = pk;   // P^T-pack: r contiguous in s
            }
        } else {
            #pragma unroll
            for (int st2 = 0; st2 < 4; ++st2) {
                float p[4];
                #pragma unroll
                for (int r = 0; r < 4; ++r) {
                    int s = s0 + st2 * 16 + quad * 4 + r;
                    bool valid = (s < plen) || (s == qcol);
                    p[r] = __builtin_amdgcn_exp2f(valid ? sf[st2][r] : -INFINITY);
                    lsum += p[r];
                }
                ushort4v pk = { f2bf(p[0]), f2bf(p[1]), f2bf(p[2]), f2bf(p[3]) };
                *(ushort4v*)(pw + st2 * 16 + quad * 4) = pk;
            }
        }

        // ---- PV: O[q][d] += P·V (A = P rows q, B = V^T rows d) ----
        #pragma unroll
        for (int ks = 0; ks < 2; ++ks) {
            short8 aP = *(const short8*)(sP + qrow * PSTR + ks * 32 + quad * 8);
            #pragma unroll
            for (int dt = 0; dt < 4; ++dt) {
                int vrow = dt * 16 + l16;
                short8 bV = *(const short8*)(sv + vrow * 64 + (((ks * 4 + quad) ^ (vrow & 7)) * 8));
                acc[dt] = __builtin_amdgcn_mfma_f32_16x16x32_bf16(aP, bV, acc[dt], 0, 0, 0);
            }
        }
    }

    // ---- epilogue: unnormalized partials ----
    lsum += __shfl_xor(lsum, 16, 64);
    lsum += __shfl_xor(lsum, 32, 64);
    if (quad == 0)
        Lp[((size_t)sp * NH + n) * QL + q0 + qrow] = lsum;

    float* ob = Op + (((size_t)sp * NH + n) * QL + q0) * DD;
    #pragma unroll
    for (int r = 0; r < 4; ++r) {
        int ql = wave * 16 + quad * 4 + r;
        #pragma unroll
        for (int dt = 0; dt < 4; ++dt)
            ob[(size_t)ql * DD + dt * 16 + l16] = acc[dt][r];
    }
}

// ---------------- combine: O = sum(Op) / sum(Lp) over contributing splits ----------------
__global__ __launch_bounds__(256) void combine(
    const float* __restrict__ Op, const float* __restrict__ Lp,
    const int* __restrict__ plen_g, float* __restrict__ Og, int nsplit, int spl)
{
    int idx = blockIdx.x * 256 + (int)threadIdx.x;    // float4 index, NH*QL*DD/4
    int d4 = idx & 15;
    int q  = (idx >> 4) & (QL - 1);
    int n  = idx >> 15;
    int plen = plen_g[n];
    int spd = q / spl;
    float4 s = {0.f, 0.f, 0.f, 0.f};
    float l = 0.f;
    for (int sp = 0; sp < nsplit; ++sp) {
        if ((sp * spl < plen) || (sp == spd)) {       // same predicate as attn early-exit
            const float* ob = Op + (((size_t)sp * NH + n) * QL + q) * DD;
            float4 v = *(const float4*)(ob + d4 * 4);
            s.x += v.x; s.y += v.y; s.z += v.z; s.w += v.w;
            l += Lp[((size_t)sp * NH + n) * QL + q];
        }
    }
    float inv = 1.0f / l;
    float4 o = { s.x * inv, s.y * inv, s.z * inv, s.w * inv };
    *(float4*)(Og + ((size_t)n * QL + q) * DD + d4 * 4) = o;
}

extern "C" void kernel_launch(void* const* d_in, const int* in_sizes, int n_in,
                              void* d_out, int out_size, void* d_ws, size_t ws_size,
                              hipStream_t stream) {
    const float* Qf   = (const float*)d_in[0];
    const float* Kf   = (const float*)d_in[1];
    const float* Vf   = (const float*)d_in[2];
    const int*   plen = (const int*)d_in[3];
    float* Og = (float*)d_out;

    char* ws = (char*)d_ws;
    unsigned short* Qb  = (unsigned short*)(ws);
    unsigned short* Kb  = (unsigned short*)(ws + (4u << 20));
    unsigned short* Vtb = (unsigned short*)(ws + (8u << 20));
    float* Op = (float*)(ws + (12u << 20));

    const size_t op_bytes = (size_t)NH * QL * DD * 4;   // 8 MB per split
    const size_t lp_bytes = (size_t)NH * QL * 4;        // 128 KB per split
    int nsplit = 1;
    if (ws_size >= (12u << 20) + 4 * (op_bytes + lp_bytes)) nsplit = 4;
    else if (ws_size >= (12u << 20) + 2 * (op_bytes + lp_bytes)) nsplit = 2;
    float* Lp = (float*)(ws + (12u << 20) + (size_t)nsplit * op_bytes);
    int spl = SL / nsplit;

    convqk<<<dim3(2048, 2), 256, 0, stream>>>(Qf, Kf, Qb, Kb);
    transv<<<512, 256, 0, stream>>>(Vf, Vtb);
    attn_mfma_split<<<dim3(NH * (QL / 64), nsplit), 256, 0, stream>>>(Qb, Kb, Vtb, plen, Op, Lp, spl);
    combine<<<2048, 256, 0, stream>>>(Op, Lp, plen, Og, nsplit, spl);
}